// Round 1
// baseline (35.575 us; speedup 1.0000x reference)
//
#include <hip/hip_runtime.h>

// OKLab -> ACEScg: per-pixel 3-vector transform on [B=8, C=3, H=1024, W=1024] fp32.
// Memory-bound: 100.7 MB in + 100.7 MB out. Strategy: float4 loads per channel
// plane (channel-planar layout), all math in registers, float4 stores.

#define B_DIM 8
#define HW (1024 * 1024)
#define QP (HW / 4)                 // float4 quads per plane = 2^18
#define NQUADS (B_DIM * QP)         // total pixel-quads = 2^21

__device__ __forceinline__ void oklab_px(float L, float A, float Bv,
                                         float& r, float& g, float& b) {
    // y = x @ M1  (row-vector convention: y_j = sum_i x_i * M1[i][j])
    float y0 = fmaf(0.2158037573f,  Bv, fmaf(0.3963377774f,  A, L));
    float y1 = fmaf(-0.0638541728f, Bv, fmaf(-0.1055613458f, A, L));
    float y2 = fmaf(-1.291485548f,  Bv, fmaf(-0.0894841775f, A, L));

    // signed cube == plain cube
    float l = y0 * y0 * y0;
    float m = y1 * y1 * y1;
    float s = y2 * y2 * y2;

    // z = y @ M2
    float z0 = fmaf(0.2309699292f, s, fmaf(-3.3077115913f, m, 4.0767416621f  * l));
    float z1 = fmaf(-0.3413193965f, s, fmaf(2.6097574011f,  m, -1.2684380046f * l));
    float z2 = fmaf(1.707614701f,  s, fmaf(-0.7034186147f, m, 0.0041960863f  * l));

    // w = z @ M3
    r = fmaf(0.0474050234857193f, z2, fmaf(0.339523761133735f,  z1, 0.613130111351449f  * z0));
    g = fmaf(0.0134571284251877f, z2, fmaf(0.916356903394254f,  z1, 0.0701050973342151f * z0));
    b = fmaf(0.869782709459968f,  z2, fmaf(0.109559786350199f,  z1, 0.0205851228833001f * z0));
}

__global__ __launch_bounds__(256) void oklab_to_acescg_kernel(
    const float4* __restrict__ in, float4* __restrict__ out) {
    int idx = blockIdx.x * blockDim.x + threadIdx.x;
    int stride = gridDim.x * blockDim.x;
    for (int t = idx; t < NQUADS; t += stride) {
        int b = t >> 18;            // t / QP (QP = 2^18)
        int q = t & (QP - 1);       // t % QP
        const float4 xL = in[(b * 3 + 0) * QP + q];
        const float4 xA = in[(b * 3 + 1) * QP + q];
        const float4 xB = in[(b * 3 + 2) * QP + q];

        float4 oR, oG, oB;
        oklab_px(xL.x, xA.x, xB.x, oR.x, oG.x, oB.x);
        oklab_px(xL.y, xA.y, xB.y, oR.y, oG.y, oB.y);
        oklab_px(xL.z, xA.z, xB.z, oR.z, oG.z, oB.z);
        oklab_px(xL.w, xA.w, xB.w, oR.w, oG.w, oB.w);

        out[(b * 3 + 0) * QP + q] = oR;
        out[(b * 3 + 1) * QP + q] = oG;
        out[(b * 3 + 2) * QP + q] = oB;
    }
}

extern "C" void kernel_launch(void* const* d_in, const int* in_sizes, int n_in,
                              void* d_out, int out_size, void* d_ws, size_t ws_size,
                              hipStream_t stream) {
    const float4* in = (const float4*)d_in[0];
    float4* out = (float4*)d_out;
    // Grid-stride: cap blocks, each thread handles 4 quads.
    int threads = 256;
    int blocks = 2048;
    oklab_to_acescg_kernel<<<blocks, threads, 0, stream>>>(in, out);
}